// Round 3
// baseline (88.678 us; speedup 1.0000x reference)
//
#include <hip/hip_runtime.h>
#include <math.h>

#define N 512
#define D 512
#define NC 10
#define NSLICE 16           // K-slices of 32
#define KS 32               // k per slice
#define MP 132              // LDS pitch (floats) for 128-wide tile, pad 4
#define EPSF 1e-8f

// ---------------- Kernel 1: partial Gram GEMM ----------------
// grid (4,4,16): (bj, bi, slice). block 256. 128x128 tile, 8x8 reg tile,
// K-slice of 32. Writes Gp[s] partial; diagonal blocks atomicAdd norm2.
__global__ __launch_bounds__(256) void k_gram(
    const float* __restrict__ pred,
    float* __restrict__ Gp,        // [NSLICE][N][N]
    float* __restrict__ norm2) {   // [N], pre-zeroed
  __shared__ __align__(16) float As[KS][MP];
  __shared__ __align__(16) float Bs[KS][MP];

  const int bj = blockIdx.x, bi = blockIdx.y, s = blockIdx.z;
  const int t = threadIdx.x;
  const int tx = t & 15, ty = t >> 4;

  // ---- stage: load 128 rows x 32 k of A and B, transpose into LDS ----
#pragma unroll
  for (int j = 0; j < 4; j++) {
    int f = t + 256 * j;          // 0..1023
    int r = f >> 3;               // row in tile 0..127
    int q = f & 7;                // float4 index within 32-k slice
    float4 va = *(const float4*)(pred + (size_t)(bi * 128 + r) * D + s * KS + q * 4);
    float4 vb = *(const float4*)(pred + (size_t)(bj * 128 + r) * D + s * KS + q * 4);
    As[q * 4 + 0][r] = va.x; As[q * 4 + 1][r] = va.y;
    As[q * 4 + 2][r] = va.z; As[q * 4 + 3][r] = va.w;
    Bs[q * 4 + 0][r] = vb.x; Bs[q * 4 + 1][r] = vb.y;
    Bs[q * 4 + 2][r] = vb.z; Bs[q * 4 + 3][r] = vb.w;
  }
  __syncthreads();

  // ---- compute: 8x8 register tile over 32 k ----
  float acc[8][8];
#pragma unroll
  for (int r = 0; r < 8; r++)
#pragma unroll
    for (int c = 0; c < 8; c++) acc[r][c] = 0.0f;

#pragma unroll 4
  for (int k = 0; k < KS; k++) {
    float4 a0 = *(const float4*)(&As[k][ty * 8]);
    float4 a1 = *(const float4*)(&As[k][ty * 8 + 4]);
    float4 b0 = *(const float4*)(&Bs[k][tx * 8]);
    float4 b1 = *(const float4*)(&Bs[k][tx * 8 + 4]);
    float a[8] = {a0.x, a0.y, a0.z, a0.w, a1.x, a1.y, a1.z, a1.w};
    float b[8] = {b0.x, b0.y, b0.z, b0.w, b1.x, b1.y, b1.z, b1.w};
#pragma unroll
    for (int r = 0; r < 8; r++)
#pragma unroll
      for (int c = 0; c < 8; c++) acc[r][c] += a[r] * b[c];
  }

  // ---- epilogue: write partial G, accumulate diag into norm2 ----
  float* Gs = Gp + (size_t)s * N * N;
  const int n0 = bj * 128 + tx * 8;
#pragma unroll
  for (int r = 0; r < 8; r++) {
    int m = bi * 128 + ty * 8 + r;
    float4 lo = {acc[r][0], acc[r][1], acc[r][2], acc[r][3]};
    float4 hi = {acc[r][4], acc[r][5], acc[r][6], acc[r][7]};
    *(float4*)(&Gs[(size_t)m * N + n0]) = lo;
    *(float4*)(&Gs[(size_t)m * N + n0 + 4]) = hi;
  }
  if (bi == bj && tx == ty) {
#pragma unroll
    for (int r = 0; r < 8; r++)
      atomicAdd(&norm2[bi * 128 + ty * 8 + r], acc[r][r]);
  }
}

// ---------------- Kernel 2: per-row loss + global mean ----------------
__global__ __launch_bounds__(256) void k_rows(
    const float* __restrict__ Gp,
    const int* __restrict__ target,
    const float* __restrict__ norm2,
    const float* __restrict__ dist_raw,
    float* __restrict__ out) {   // out pre-zeroed
  const int i = blockIdx.x;
  const int tid = threadIdx.x;

  __shared__ float s_a[N];   // compacted cos+margin over negatives
  __shared__ float s_p[N];   // compacted cos over positives
  __shared__ float s_cp[NC];
  __shared__ int s_np, s_nn;

  if (tid == 0) {
    s_np = 0; s_nn = 0;
    float acc = 0.0f;
    s_cp[0] = 0.0f;
    for (int c = 0; c < NC - 1; c++) {
      acc += log1pf(expf(dist_raw[c]));
      s_cp[c + 1] = acc;
    }
  }
  __syncthreads();

  const int ti = target[i];
  const float inv_i = 1.0f / fmaxf(sqrtf(norm2[i]), EPSF);
  const float cpi = s_cp[ti];

  for (int j = tid; j < N; j += 256) {
    float g = 0.0f;
#pragma unroll
    for (int s = 0; s < NSLICE; s++)
      g += Gp[(size_t)s * N * N + (size_t)i * N + j];
    float cosv = g * inv_i * (1.0f / fmaxf(sqrtf(norm2[j]), EPSF));
    int tj = target[j];
    if (tj != ti) {
      float m = fabsf(cpi - s_cp[tj]);
      int idx = atomicAdd(&s_nn, 1);
      s_a[idx] = cosv + m;
    } else if (j != i) {
      int idx = atomicAdd(&s_np, 1);
      s_p[idx] = cosv;
    }
  }
  __syncthreads();

  const int np = s_np, nn = s_nn;
  float a0 = (tid < nn) ? s_a[tid] : -1e30f;
  float a1 = (tid + 256 < nn) ? s_a[tid + 256] : -1e30f;
  float acc = 0.0f;
  for (int kk = 0; kk < np; kk++) {
    float ck = s_p[kk];
    acc += fmaxf(a0 - ck, 0.0f) + fmaxf(a1 - ck, 0.0f);
  }

  for (int off = 32; off > 0; off >>= 1) acc += __shfl_down(acc, off);
  __shared__ float s_part[4];
  if ((tid & 63) == 0) s_part[tid >> 6] = acc;
  __syncthreads();
  if (tid == 0) {
    float total = s_part[0] + s_part[1] + s_part[2] + s_part[3];
    if (np > 0 && nn > 0) {
      float r = total / ((float)nn * (float)nn * (float)np);
      atomicAdd(out, r / (float)N);
    }
  }
}

extern "C" void kernel_launch(void* const* d_in, const int* in_sizes, int n_in,
                              void* d_out, int out_size, void* d_ws, size_t ws_size,
                              hipStream_t stream) {
  const float* pred = (const float*)d_in[0];
  const float* dist_raw = (const float*)d_in[1];
  const int* target = (const int*)d_in[2];
  float* out = (float*)d_out;

  float* Gp = (float*)d_ws;                       // 16 * N*N floats = 16 MB
  float* norm2 = Gp + (size_t)NSLICE * N * N;     // N floats

  hipMemsetAsync(norm2, 0, N * sizeof(float), stream);
  hipMemsetAsync(out, 0, sizeof(float), stream);

  dim3 ggrid(4, 4, NSLICE);
  k_gram<<<ggrid, 256, 0, stream>>>(pred, Gp, norm2);
  k_rows<<<N, 256, 0, stream>>>(Gp, target, norm2, dist_raw, out);
}

// Round 4
// 85.532 us; speedup vs baseline: 1.0368x; 1.0368x over previous
//
#include <hip/hip_runtime.h>
#include <math.h>

#define N 512
#define D 512
#define NC 10
#define EPSF 1e-8f
#define PITCH 132   // 128 + 4 pad (floats); rows 16B-aligned, conflict-free per 8-lane group

// ---------------- Kernel 1: Gram GEMM  G = pred @ pred^T ----------------
// grid (16,16), block 256 (4 waves). 32x32 tile; K=512 split across waves
// (wave w handles k in [w*32, w*32+32) of each 128-k chunk). Each wave: 4x4
// register tile with strided rows/cols (m = ty+8r, n = tx+8c). Cross-wave
// reduction via LDS. Diagonal blocks emit inv_n; block (0,0) zeroes out.
__global__ __launch_bounds__(256) void k_gram(
    const float* __restrict__ pred,
    float* __restrict__ G,
    float* __restrict__ inv_n,
    float* __restrict__ out) {
  __shared__ __align__(16) float As[32][PITCH];
  __shared__ __align__(16) float Bs[32][PITCH];
  __shared__ __align__(16) float red[4][32][36];

  const int bj = blockIdx.x, bi = blockIdx.y;
  const int t = threadIdx.x;
  const int w = t >> 6;            // wave 0..3
  const int lane = t & 63;
  const int tx = lane & 7;         // 0..7
  const int ty = lane >> 3;        // 0..7

  const float* Arow = pred + (size_t)(bi * 32) * D;
  const float* Brow = pred + (size_t)(bj * 32) * D;

  float acc[4][4];
#pragma unroll
  for (int r = 0; r < 4; r++)
#pragma unroll
    for (int c = 0; c < 4; c++) acc[r][c] = 0.0f;

  // staging assignment: element f in [0,1024): row = f>>5, k4 = f&31
  const int srow = t >> 5 >= 0 ? 0 : 0;  // (computed per j below)

  float4 pa[4], pb[4];
#pragma unroll
  for (int j = 0; j < 4; j++) {
    int f = t + 256 * j;
    int row = f >> 5, k4 = f & 31;
    pa[j] = *(const float4*)(Arow + (size_t)row * D + k4 * 4);
    pb[j] = *(const float4*)(Brow + (size_t)row * D + k4 * 4);
  }

  for (int ch = 0; ch < 4; ch++) {
#pragma unroll
    for (int j = 0; j < 4; j++) {
      int f = t + 256 * j;
      int row = f >> 5, k4 = f & 31;
      *(float4*)(&As[row][k4 * 4]) = pa[j];
      *(float4*)(&Bs[row][k4 * 4]) = pb[j];
    }
    __syncthreads();

    if (ch < 3) {  // prefetch next 128-k chunk
      int k0 = (ch + 1) * 128;
#pragma unroll
      for (int j = 0; j < 4; j++) {
        int f = t + 256 * j;
        int row = f >> 5, k4 = f & 31;
        pa[j] = *(const float4*)(Arow + (size_t)row * D + k0 + k4 * 4);
        pb[j] = *(const float4*)(Brow + (size_t)row * D + k0 + k4 * 4);
      }
    }

    const int kb = w * 32;  // this wave's k-slice within the chunk
#pragma unroll
    for (int kk = 0; kk < 32; kk += 4) {
      float4 av[4], bv[4];
#pragma unroll
      for (int r = 0; r < 4; r++) av[r] = *(const float4*)(&As[ty + 8 * r][kb + kk]);
#pragma unroll
      for (int c = 0; c < 4; c++) bv[c] = *(const float4*)(&Bs[tx + 8 * c][kb + kk]);
#pragma unroll
      for (int r = 0; r < 4; r++)
#pragma unroll
        for (int c = 0; c < 4; c++)
          acc[r][c] += av[r].x * bv[c].x + av[r].y * bv[c].y +
                       av[r].z * bv[c].z + av[r].w * bv[c].w;
    }
    __syncthreads();
  }

  // ---- cross-wave reduction ----
#pragma unroll
  for (int r = 0; r < 4; r++)
#pragma unroll
    for (int c = 0; c < 4; c++)
      red[w][ty + 8 * r][tx + 8 * c] = acc[r][c];
  __syncthreads();

  const int m = t >> 3;            // 0..31
  const int n4 = (t & 7) * 4;      // 0,4,..,28
  float4 s0 = *(const float4*)(&red[0][m][n4]);
  float4 s1 = *(const float4*)(&red[1][m][n4]);
  float4 s2 = *(const float4*)(&red[2][m][n4]);
  float4 s3 = *(const float4*)(&red[3][m][n4]);
  float4 s;
  s.x = (s0.x + s1.x) + (s2.x + s3.x);
  s.y = (s0.y + s1.y) + (s2.y + s3.y);
  s.z = (s0.z + s1.z) + (s2.z + s3.z);
  s.w = (s0.w + s1.w) + (s2.w + s3.w);

  *(float4*)(&G[(size_t)(bi * 32 + m) * N + bj * 32 + n4]) = s;

  if (bi == bj && m >= n4 && m < n4 + 4) {
    float dv = (&s.x)[m - n4];  // diagonal element G[m][m]
    inv_n[bi * 32 + m] = 1.0f / fmaxf(sqrtf(dv), EPSF);
  }
  if (bi == 0 && bj == 0 && t == 0) out[0] = 0.0f;
}

// ---------------- Kernel 2: per-row loss + global mean ----------------
__global__ __launch_bounds__(256) void k_rows(
    const float* __restrict__ G,
    const int* __restrict__ target,
    const float* __restrict__ inv_n,
    const float* __restrict__ dist_raw,
    float* __restrict__ out) {   // zeroed by k_gram
  const int i = blockIdx.x;
  const int tid = threadIdx.x;

  __shared__ float s_a[N];   // compacted cos+margin over negatives
  __shared__ float s_p[N];   // compacted cos over positives
  __shared__ float s_cp[NC];
  __shared__ int s_np, s_nn;

  if (tid == 0) {
    s_np = 0; s_nn = 0;
    float acc = 0.0f;
    s_cp[0] = 0.0f;
    for (int c = 0; c < NC - 1; c++) {
      acc += log1pf(expf(dist_raw[c]));
      s_cp[c + 1] = acc;
    }
  }
  __syncthreads();

  const int ti = target[i];
  const float inv_i = inv_n[i];
  const float cpi = s_cp[ti];

  for (int j = tid; j < N; j += 256) {
    float cosv = G[(size_t)i * N + j] * inv_i * inv_n[j];
    int tj = target[j];
    if (tj != ti) {
      float mg = fabsf(cpi - s_cp[tj]);
      int idx = atomicAdd(&s_nn, 1);
      s_a[idx] = cosv + mg;
    } else if (j != i) {
      int idx = atomicAdd(&s_np, 1);
      s_p[idx] = cosv;
    }
  }
  __syncthreads();

  const int np = s_np, nn = s_nn;
  float a0 = (tid < nn) ? s_a[tid] : -1e30f;
  float a1 = (tid + 256 < nn) ? s_a[tid + 256] : -1e30f;
  float acc = 0.0f;
  for (int kk = 0; kk < np; kk++) {
    float ck = s_p[kk];  // LDS broadcast
    acc += fmaxf(a0 - ck, 0.0f) + fmaxf(a1 - ck, 0.0f);
  }

  for (int off = 32; off > 0; off >>= 1) acc += __shfl_down(acc, off);
  __shared__ float s_part[4];
  if ((tid & 63) == 0) s_part[tid >> 6] = acc;
  __syncthreads();
  if (tid == 0) {
    float total = s_part[0] + s_part[1] + s_part[2] + s_part[3];
    if (np > 0 && nn > 0) {
      float r = total / ((float)nn * (float)nn * (float)np);
      atomicAdd(out, r / (float)N);
    }
  }
}

extern "C" void kernel_launch(void* const* d_in, const int* in_sizes, int n_in,
                              void* d_out, int out_size, void* d_ws, size_t ws_size,
                              hipStream_t stream) {
  const float* pred = (const float*)d_in[0];
  const float* dist_raw = (const float*)d_in[1];
  const int* target = (const int*)d_in[2];
  float* out = (float*)d_out;

  float* G = (float*)d_ws;                 // N*N floats = 1 MB
  float* inv_n = G + (size_t)N * N;        // N floats

  dim3 ggrid(16, 16);
  k_gram<<<ggrid, 256, 0, stream>>>(pred, G, inv_n, out);
  k_rows<<<N, 256, 0, stream>>>(G, target, inv_n, dist_raw, out);
}